// Round 12
// baseline (138.732 us; speedup 1.0000x reference)
//
#include <hip/hip_runtime.h>
#include <math.h>

#define H 1024
#define W 1024
#define OH 1016
#define OW 1016
#define BH 8           // output rows per band (1016 = 8*127 exact, no tail)
#define NBANDS 127
#define NCHUNK 2       // 2 column chunks: jc = 0, 504 (8-col overlap, benign)
#define NIMG 8
#define NWG (NBANDS*NCHUNK*NIMG)   // 2032, divisible by 8 (bijective XCD swizzle)
#define EPS 1e-6f
#define INV25 (1.0f/25.0f)

// R12: 8-col lanes. Each lane owns 8 output cols (span-16 input, 4x b128/row)
// -> 1.5x fewer load instrs/output and ~25% less VALU/output than 4-col lanes.
// One wave covers 512 cols; 2 chunks/row. No lane clamping anywhere.
// dx/dy ring: two lane-indexed float4 arrays dqA/dqB[5][2][64] (16B lane
// stride -> conflict-free; reads are same-lane same-address vs own writes ->
// ordered without fences). Halo-4 old values via __shfl_down(own,1); lane 63
// uses a 160B seam it alone writes/reads.
// R5 lesson: tight launch_bounds forced spill. Keep (64,2) (VGPR cap 256).
// R6 lesson: no sched fences. R8 lesson: keep XCD swizzle.
// R11 lesson: raw-row LDS ring trades global instrs for DS instrs+conflicts
// +fences at a net LOSS; center/old rows come from global (L2-resident).

__device__ __forceinline__ float4 ld4(const float* p){ return *reinterpret_cast<const float4*>(p); }
__device__ __forceinline__ void st4(float* p, float4 v){ *reinterpret_cast<float4*>(p) = v; }

__device__ __forceinline__ void load16(const float* p, float v[16]) {
    float4 a = ld4(p), b = ld4(p + 4), c = ld4(p + 8), d = ld4(p + 12);
    v[0]=a.x;  v[1]=a.y;  v[2]=a.z;  v[3]=a.w;
    v[4]=b.x;  v[5]=b.y;  v[6]=b.z;  v[7]=b.w;
    v[8]=c.x;  v[9]=c.y;  v[10]=c.z; v[11]=c.w;
    v[12]=d.x; v[13]=d.y; v[14]=d.z; v[15]=d.w;
}

__global__ __launch_bounds__(64, 2)
void yiq_gngc_w8(const float* __restrict__ x, const float* __restrict__ y,
                 float* __restrict__ out, long long Nper)
{
    __shared__ __align__(16) float4 dqA[5][2][64];   // 10240 B: old dxn[0..3]/dyn[0..3]
    __shared__ __align__(16) float4 dqB[5][2][64];   // 10240 B: old dxn[4..7]/dyn[4..7]
    __shared__ __align__(16) float seam[5][2][4];    // 160 B: lane63's dxn[8..11]
    const int t = (int)threadIdx.x;

    // ---- XCD-aware bijective swizzle (NWG % 8 == 0) ----
    const int wg  = (int)blockIdx.x;
    const int nid = (wg & 7) * (NWG / 8) + (wg >> 3);
    const int band  = nid % NBANDS;
    const int rest  = nid / NBANDS;       // 0..15
    const int chunk = rest & 1;
    const int b     = rest >> 1;          // image 0..7

    const int jc = chunk * 504;           // 0 or 504; j0 max = 504+504 = 1008
    const int j0 = jc + 8 * t;            // outputs j0..j0+7; inputs j0..j0+15 (max 1023)
    const int i0 = band * BH;
    const float* xb = x + (size_t)b * (H * W) + j0;
    const float* yb = y + (size_t)b * (H * W) + j0;

    float cs_x[16], cs_y[16];             // 5-row col sums, cols j0..j0+15
    float cp1[12], cp2[12], cp3[12];      // 5-row product col sums, dx cols j0..j0+11
    #pragma unroll
    for (int k = 0; k < 16; ++k) { cs_x[k] = 0.f; cs_y[k] = 0.f; }
    #pragma unroll
    for (int k = 0; k < 12; ++k) { cp1[k] = 0.f; cp2[k] = 0.f; cp3[k] = 0.f; }

    // ---- zero ring slot 4 (the "row -1" subtracted at it=0) ----
    {
        float4 z = make_float4(0.f, 0.f, 0.f, 0.f);
        dqA[4][0][t] = z; dqA[4][1][t] = z;
        dqB[4][0][t] = z; dqB[4][1][t] = z;
        if (t == 63) { st4(&seam[4][0][0], z); st4(&seam[4][1][0], z); }
    }

    // ---- initial input column sums over rows i0..i0+4 (x then y) ----
    #pragma unroll
    for (int r = 0; r < 5; ++r) {
        float vx[16];
        load16(xb + (size_t)(i0 + r) * W, vx);
        #pragma unroll
        for (int k = 0; k < 16; ++k) cs_x[k] += vx[k];
    }
    #pragma unroll
    for (int r = 0; r < 5; ++r) {
        float vy[16];
        load16(yb + (size_t)(i0 + r) * W, vy);
        #pragma unroll
        for (int k = 0; k < 16; ++k) cs_y[k] += vy[k];
    }

    // ---- prime dx/dy rows i0..i0+3 into ring slots 0..3; accumulate cp ----
    #pragma unroll
    for (int pr = 0; pr < 4; ++pr) {
        float dxn[12], dyn[12];
        {   // x half: center, dxn, slide
            float xc[16], nx[16], ox[16];
            load16(xb + (size_t)(i0 + pr + 2) * W, xc);
            load16(xb + (size_t)(i0 + pr + 5) * W, nx);
            load16(xb + (size_t)(i0 + pr) * W, ox);
            #pragma unroll
            for (int k = 0; k < 12; ++k) {
                float sx = cs_x[k] + cs_x[k+1] + cs_x[k+2] + cs_x[k+3] + cs_x[k+4];
                dxn[k] = xc[k + 2] - sx * INV25;
            }
            #pragma unroll
            for (int k = 0; k < 16; ++k) cs_x[k] += nx[k] - ox[k];
        }
        {   // y half
            float yc[16], ny[16], oy[16];
            load16(yb + (size_t)(i0 + pr + 2) * W, yc);
            load16(yb + (size_t)(i0 + pr + 5) * W, ny);
            load16(yb + (size_t)(i0 + pr) * W, oy);
            #pragma unroll
            for (int k = 0; k < 12; ++k) {
                float sy = cs_y[k] + cs_y[k+1] + cs_y[k+2] + cs_y[k+3] + cs_y[k+4];
                dyn[k] = yc[k + 2] - sy * INV25;
            }
            #pragma unroll
            for (int k = 0; k < 16; ++k) cs_y[k] += ny[k] - oy[k];
        }
        #pragma unroll
        for (int k = 0; k < 12; ++k) {
            cp1[k] += dxn[k] * dyn[k];
            cp2[k] += dxn[k] * dxn[k];
            cp3[k] += dyn[k] * dyn[k];
        }
        dqA[pr][0][t] = make_float4(dxn[0], dxn[1], dxn[2],  dxn[3]);
        dqA[pr][1][t] = make_float4(dyn[0], dyn[1], dyn[2],  dyn[3]);
        dqB[pr][0][t] = make_float4(dxn[4], dxn[5], dxn[6],  dxn[7]);
        dqB[pr][1][t] = make_float4(dyn[4], dyn[5], dyn[6],  dyn[7]);
        if (t == 63) {
            st4(&seam[pr][0][0], make_float4(dxn[8], dxn[9], dxn[10], dxn[11]));
            st4(&seam[pr][1][0], make_float4(dyn[8], dyn[9], dyn[10], dyn[11]));
        }
    }

    float* ob = out + (size_t)b * ((size_t)OH * OW) + j0;

    // ---- main loop: output rows i0..i0+7 (fully unrolled, static ring slots) ----
    #pragma unroll
    for (int it = 0; it < BH; ++it) {
        const int i = i0 + it;
        const int s = (it + 4) % 5;       // ring slot of dropped row i-1 == new row i+4
        const bool slide = (it < BH - 1);

        float dxn[12], dyn[12];
        {   // x half: center row i+6 (max 1021), new i+9 (max 1023), old i+4
            float xc[16], nx[16], ox[16];
            load16(xb + (size_t)(i + 6) * W, xc);
            if (slide) {
                load16(xb + (size_t)(i + 9) * W, nx);
                load16(xb + (size_t)(i + 4) * W, ox);
            }
            #pragma unroll
            for (int k = 0; k < 12; ++k) {
                float sx = cs_x[k] + cs_x[k+1] + cs_x[k+2] + cs_x[k+3] + cs_x[k+4];
                dxn[k] = xc[k + 2] - sx * INV25;
            }
            if (slide) {
                #pragma unroll
                for (int k = 0; k < 16; ++k) cs_x[k] += nx[k] - ox[k];
            }
        }
        {   // y half
            float yc[16], ny[16], oy[16];
            load16(yb + (size_t)(i + 6) * W, yc);
            if (slide) {
                load16(yb + (size_t)(i + 9) * W, ny);
                load16(yb + (size_t)(i + 4) * W, oy);
            }
            #pragma unroll
            for (int k = 0; k < 12; ++k) {
                float sy = cs_y[k] + cs_y[k+1] + cs_y[k+2] + cs_y[k+3] + cs_y[k+4];
                dyn[k] = yc[k + 2] - sy * INV25;
            }
            if (slide) {
                #pragma unroll
                for (int k = 0; k < 16; ++k) cs_y[k] += ny[k] - oy[k];
            }
        }

        // --- old dx/dy (row i-1): own 8 from ring (same-lane same-address ->
        //     ordered vs the write below), halo 4 via shfl; lane63 from seam ---
        float4 oax = dqA[s][0][t];
        float4 oay = dqA[s][1][t];
        float4 obx = dqB[s][0][t];
        float4 oby = dqB[s][1][t];
        float hx0 = __shfl_down(oax.x, 1), hx1 = __shfl_down(oax.y, 1);
        float hx2 = __shfl_down(oax.z, 1), hx3 = __shfl_down(oax.w, 1);
        float hy0 = __shfl_down(oay.x, 1), hy1 = __shfl_down(oay.y, 1);
        float hy2 = __shfl_down(oay.z, 1), hy3 = __shfl_down(oay.w, 1);
        if (t == 63) {
            float4 shx = ld4(&seam[s][0][0]);
            float4 shy = ld4(&seam[s][1][0]);
            hx0 = shx.x; hx1 = shx.y; hx2 = shx.z; hx3 = shx.w;
            hy0 = shy.x; hy1 = shy.y; hy2 = shy.z; hy3 = shy.w;
        }
        // overwrite ring slot s with the new row
        dqA[s][0][t] = make_float4(dxn[0], dxn[1], dxn[2],  dxn[3]);
        dqA[s][1][t] = make_float4(dyn[0], dyn[1], dyn[2],  dyn[3]);
        dqB[s][0][t] = make_float4(dxn[4], dxn[5], dxn[6],  dxn[7]);
        dqB[s][1][t] = make_float4(dyn[4], dyn[5], dyn[6],  dyn[7]);
        if (t == 63) {
            st4(&seam[s][0][0], make_float4(dxn[8], dxn[9], dxn[10], dxn[11]));
            st4(&seam[s][1][0], make_float4(dyn[8], dyn[9], dyn[10], dyn[11]));
        }

        // slide product column sums: + new row, - old row
        float odx[12] = {oax.x, oax.y, oax.z, oax.w, obx.x, obx.y, obx.z, obx.w,
                         hx0, hx1, hx2, hx3};
        float ody[12] = {oay.x, oay.y, oay.z, oay.w, oby.x, oby.y, oby.z, oby.w,
                         hy0, hy1, hy2, hy3};
        #pragma unroll
        for (int k = 0; k < 12; ++k) {
            cp1[k] += dxn[k] * dyn[k] - odx[k] * ody[k];
            cp2[k] += dxn[k] * dxn[k] - odx[k] * odx[k];
            cp3[k] += dyn[k] * dyn[k] - ody[k] * ody[k];
        }

        // finalize output row i, cols j0..j0+7
        float co[8], vv[8], cc[8];
        #pragma unroll
        for (int q = 0; q < 8; ++q) {
            float c_ = (cp1[q] + cp1[q+1] + cp1[q+2] + cp1[q+3] + cp1[q+4]) * INV25;
            float vx = (cp2[q] + cp2[q+1] + cp2[q+2] + cp2[q+3] + cp2[q+4]) * INV25;
            float vy = (cp3[q] + cp3[q+1] + cp3[q+2] + cp3[q+3] + cp3[q+4]) * INV25;
            float v  = sqrtf(vx * vy);
            bool lo  = v < EPS;
            float cv = lo ? 0.f : c_;
            float vs = lo ? EPS : v;
            float r_ = cv / vs;
            r_ = r_ < 0.f ? 0.f : (r_ > 1.f ? 1.f : r_);
            co[q] = r_; vv[q] = vs; cc[q] = cv;
        }
        float* o = ob + (size_t)i * OW;
        st4(o,                make_float4(co[0], co[1], co[2], co[3]));
        st4(o + 4,            make_float4(co[4], co[5], co[6], co[7]));
        st4(o + Nper,         make_float4(vv[0], vv[1], vv[2], vv[3]));
        st4(o + Nper + 4,     make_float4(vv[4], vv[5], vv[6], vv[7]));
        st4(o + 2 * Nper,     make_float4(cc[0], cc[1], cc[2], cc[3]));
        st4(o + 2 * Nper + 4, make_float4(cc[4], cc[5], cc[6], cc[7]));
    }
}

extern "C" void kernel_launch(void* const* d_in, const int* in_sizes, int n_in,
                              void* d_out, int out_size, void* d_ws, size_t ws_size,
                              hipStream_t stream) {
    const float* x = (const float*)d_in[0];
    const float* y = (const float*)d_in[1];
    // mask (d_in[2]) unused by the reference's channels==1 path
    float* out = (float*)d_out;
    const long long Nper = (long long)out_size / 3;   // elements per output array
    yiq_gngc_w8<<<dim3(NWG), dim3(64), 0, stream>>>(x, y, out, Nper);
}

// Round 13
// 59.717 us; speedup vs baseline: 2.3232x; 2.3232x over previous
//
#include <hip/hip_runtime.h>
#include <math.h>

#define H 1024
#define W 1024
#define OH 1016
#define OW 1016
#define BH 8           // output rows per band (1016 = 8*127 exact)
#define NBANDS 127
#define NB2 64         // band-pairs per chunk (2 bands/block; last pair half-idle)
#define NCHUNK 4       // 4 column chunks of 256 output cols
#define NIMG 8
#define NWG (NB2*NCHUNK*NIMG)   // 2048, divisible by 8 (bijective XCD swizzle)
#define EPS 1e-6f
#define INV25 (1.0f/25.0f)

// R13 = R8's exact per-wave program, but TWO independent waves per block
// (128 threads) on adjacent bands, sharing one 21 KB LDS allocation
// (ring[2][...], wave-indexed; no inter-wave interaction; still barrier-free).
// Purpose: occupancy is pinned at ~6 waves/CU despite caps of 14 (LDS) and
// 16 (VGPR). If the limiter is a per-CU workgroup-slot count, 2-wave blocks
// double resident waves; if it is an effective 64 KiB LDS pool, residency is
// unchanged (3 blocks x 2 waves = 6) -- a no-regression hedge either way.
// R5/R9/R12 lesson: >~128 VGPR of per-lane state spills. R8 economics final.
// R6 lesson: no sched fences. R8 lesson: keep XCD swizzle.
// R11 lesson: raw-row LDS ring is a net loss; rows come from global (L2).

__device__ __forceinline__ float4 ld4(const float* p){ return *reinterpret_cast<const float4*>(p); }
__device__ __forceinline__ void st4(float* p, float4 v){ *reinterpret_cast<float4*>(p) = v; }

__device__ __forceinline__ void load12(const float* p, float v[12]) {
    float4 a = ld4(p), b = ld4(p + 4), c = ld4(p + 8);
    v[0]=a.x; v[1]=a.y; v[2]=a.z;  v[3]=a.w;
    v[4]=b.x; v[5]=b.y; v[6]=b.z;  v[7]=b.w;
    v[8]=c.x; v[9]=c.y; v[10]=c.z; v[11]=c.w;
}

__global__ __launch_bounds__(128, 2)
void yiq_gngc_w2(const float* __restrict__ x, const float* __restrict__ y,
                 float* __restrict__ out, long long Nper)
{
    __shared__ __align__(16) float ring[2][5][2][264];   // 21120 B (per-wave halves)
    const int tid = (int)threadIdx.x;
    const int w   = tid >> 6;          // wave 0/1
    const int t   = tid & 63;          // lane

    // ---- XCD-aware bijective swizzle (NWG % 8 == 0) ----
    const int wg  = (int)blockIdx.x;
    const int nid = (wg & 7) * (NWG / 8) + (wg >> 3);
    const int b2    = nid % NB2;           // band-pair 0..63
    const int rest  = nid / NB2;           // 0..31
    const int chunk = rest & 3;
    const int b     = rest >> 2;           // image 0..7

    const int band = b2 * 2 + w;
    if (band >= NBANDS) return;            // lone idle wave in last pair; no barriers -> safe

    const int jc = chunk * 256;
    const int maxj = (jc + 252 < OW - 4) ? (jc + 252) : (OW - 4);  // 1012 on last chunk
    int j0 = jc + 4 * t; if (j0 > maxj) j0 = maxj;    // clamped lanes duplicate (benign)
    const bool lastlane = (j0 == maxj);               // owns the 4-col ring seam
    const int rel = j0 - jc;                          // 0..252
    const int i0 = band * BH;
    const float* xb = x + (size_t)b * (H * W) + j0;
    const float* yb = y + (size_t)b * (H * W) + j0;

    float cs_x[12], cs_y[12];
    float cp1[8], cp2[8], cp3[8];
    #pragma unroll
    for (int k = 0; k < 12; ++k) { cs_x[k] = 0.f; cs_y[k] = 0.f; }
    #pragma unroll
    for (int k = 0; k < 8; ++k) { cp1[k] = 0.f; cp2[k] = 0.f; cp3[k] = 0.f; }

    // ---- zero ring slot 4 (the "row -1" subtracted at it=0) ----
    {
        float4 z = make_float4(0.f, 0.f, 0.f, 0.f);
        st4(&ring[w][4][0][rel], z); st4(&ring[w][4][1][rel], z);
        if (lastlane) { st4(&ring[w][4][0][rel + 4], z); st4(&ring[w][4][1][rel + 4], z); }
    }

    // ---- initial input column sums over rows i0..i0+4 (x then y) ----
    #pragma unroll
    for (int r = 0; r < 5; ++r) {
        float vx[12];
        load12(xb + (size_t)(i0 + r) * W, vx);
        #pragma unroll
        for (int k = 0; k < 12; ++k) cs_x[k] += vx[k];
    }
    #pragma unroll
    for (int r = 0; r < 5; ++r) {
        float vy[12];
        load12(yb + (size_t)(i0 + r) * W, vy);
        #pragma unroll
        for (int k = 0; k < 12; ++k) cs_y[k] += vy[k];
    }

    // ---- prime dx/dy rows i0..i0+3 into ring slots 0..3; accumulate cp ----
    #pragma unroll
    for (int pr = 0; pr < 4; ++pr) {
        float xc[12], yc[12];
        load12(xb + (size_t)(i0 + pr + 2) * W, xc);   // center row
        load12(yb + (size_t)(i0 + pr + 2) * W, yc);
        float dxn[8], dyn[8];
        #pragma unroll
        for (int k = 0; k < 8; ++k) {
            float sx = cs_x[k] + cs_x[k+1] + cs_x[k+2] + cs_x[k+3] + cs_x[k+4];
            float sy = cs_y[k] + cs_y[k+1] + cs_y[k+2] + cs_y[k+3] + cs_y[k+4];
            dxn[k] = xc[k + 2] - sx * INV25;
            dyn[k] = yc[k + 2] - sy * INV25;
            cp1[k] += dxn[k] * dyn[k];
            cp2[k] += dxn[k] * dxn[k];
            cp3[k] += dyn[k] * dyn[k];
        }
        st4(&ring[w][pr][0][rel], make_float4(dxn[0], dxn[1], dxn[2], dxn[3]));
        st4(&ring[w][pr][1][rel], make_float4(dyn[0], dyn[1], dyn[2], dyn[3]));
        if (lastlane) {
            st4(&ring[w][pr][0][rel + 4], make_float4(dxn[4], dxn[5], dxn[6], dxn[7]));
            st4(&ring[w][pr][1][rel + 4], make_float4(dyn[4], dyn[5], dyn[6], dyn[7]));
        }
        // slide cs: add row i0+pr+5, drop row i0+pr (x-pair then y-pair)
        {
            float nx[12], ox[12];
            load12(xb + (size_t)(i0 + pr + 5) * W, nx);
            load12(xb + (size_t)(i0 + pr) * W, ox);
            #pragma unroll
            for (int k = 0; k < 12; ++k) cs_x[k] += nx[k] - ox[k];
        }
        {
            float ny[12], oy[12];
            load12(yb + (size_t)(i0 + pr + 5) * W, ny);
            load12(yb + (size_t)(i0 + pr) * W, oy);
            #pragma unroll
            for (int k = 0; k < 12; ++k) cs_y[k] += ny[k] - oy[k];
        }
    }

    float* ob = out + (size_t)b * ((size_t)OH * OW) + j0;

    // ---- main loop: output rows i0..i0+7 (fully unrolled, static ring slots) ----
    #pragma unroll
    for (int it = 0; it < BH; ++it) {
        const int i = i0 + it;
        const int s = (it + 4) % 5;                  // slot of dropped row i-1 == new row i+4

        // center row for new dx/dy row i+4  (max row 1021)
        float xc[12], yc[12];
        load12(xb + (size_t)(i + 6) * W, xc);
        load12(yb + (size_t)(i + 6) * W, yc);

        // --- old dx/dy (row i-1): own 4 from LDS (same-address as the write
        //     below -> compiler-ordered), halo 4 via shfl from lane t+1 ---
        float4 oox = ld4(&ring[w][s][0][rel]);
        float4 ooy = ld4(&ring[w][s][1][rel]);
        float hx0 = __shfl_down(oox.x, 1), hx1 = __shfl_down(oox.y, 1);
        float hx2 = __shfl_down(oox.z, 1), hx3 = __shfl_down(oox.w, 1);
        float hy0 = __shfl_down(ooy.x, 1), hy1 = __shfl_down(ooy.y, 1);
        float hy2 = __shfl_down(ooy.z, 1), hy3 = __shfl_down(ooy.w, 1);
        if (lastlane) {   // seam lane: halo from its own rel+4 slot (same-address ordered)
            float4 dhx = ld4(&ring[w][s][0][rel + 4]);
            float4 dhy = ld4(&ring[w][s][1][rel + 4]);
            hx0 = dhx.x; hx1 = dhx.y; hx2 = dhx.z; hx3 = dhx.w;
            hy0 = dhy.x; hy1 = dhy.y; hy2 = dhy.z; hy3 = dhy.w;
        }

        // new dx/dy row i+4 (8 halo cols, in registers)
        float dxn[8], dyn[8];
        #pragma unroll
        for (int k = 0; k < 8; ++k) {
            float sx = cs_x[k] + cs_x[k+1] + cs_x[k+2] + cs_x[k+3] + cs_x[k+4];
            float sy = cs_y[k] + cs_y[k+1] + cs_y[k+2] + cs_y[k+3] + cs_y[k+4];
            dxn[k] = xc[k + 2] - sx * INV25;
            dyn[k] = yc[k + 2] - sy * INV25;
        }
        st4(&ring[w][s][0][rel], make_float4(dxn[0], dxn[1], dxn[2], dxn[3]));
        st4(&ring[w][s][1][rel], make_float4(dyn[0], dyn[1], dyn[2], dyn[3]));
        if (lastlane) {
            st4(&ring[w][s][0][rel + 4], make_float4(dxn[4], dxn[5], dxn[6], dxn[7]));
            st4(&ring[w][s][1][rel + 4], make_float4(dyn[4], dyn[5], dyn[6], dyn[7]));
        }

        // slide product column sums: + new row, - old row
        float odx[8] = {oox.x, oox.y, oox.z, oox.w, hx0, hx1, hx2, hx3};
        float ody[8] = {ooy.x, ooy.y, ooy.z, ooy.w, hy0, hy1, hy2, hy3};
        #pragma unroll
        for (int k = 0; k < 8; ++k) {
            cp1[k] += dxn[k] * dyn[k] - odx[k] * ody[k];
            cp2[k] += dxn[k] * dxn[k] - odx[k] * odx[k];
            cp3[k] += dyn[k] * dyn[k] - ody[k] * ody[k];
        }

        // finalize output row i, cols j0..j0+3
        float co[4], vv[4], cc[4];
        #pragma unroll
        for (int q = 0; q < 4; ++q) {
            float c_ = (cp1[q] + cp1[q+1] + cp1[q+2] + cp1[q+3] + cp1[q+4]) * INV25;
            float vx = (cp2[q] + cp2[q+1] + cp2[q+2] + cp2[q+3] + cp2[q+4]) * INV25;
            float vy = (cp3[q] + cp3[q+1] + cp3[q+2] + cp3[q+3] + cp3[q+4]) * INV25;
            float v  = sqrtf(vx * vy);
            bool lo  = v < EPS;
            float cv = lo ? 0.f : c_;
            float vs = lo ? EPS : v;
            float r_ = cv / vs;
            r_ = r_ < 0.f ? 0.f : (r_ > 1.f ? 1.f : r_);
            co[q] = r_; vv[q] = vs; cc[q] = cv;
        }
        float* o = ob + (size_t)i * OW;
        st4(o,            make_float4(co[0], co[1], co[2], co[3]));
        st4(o + Nper,     make_float4(vv[0], vv[1], vv[2], vv[3]));
        st4(o + 2 * Nper, make_float4(cc[0], cc[1], cc[2], cc[3]));

        // slide input column sums: add row i+9 (max 1023), drop row i+4
        if (it < BH - 1) {
            {
                float nx[12], oxr[12];
                load12(xb + (size_t)(i + 9) * W, nx);
                load12(xb + (size_t)(i + 4) * W, oxr);
                #pragma unroll
                for (int k = 0; k < 12; ++k) cs_x[k] += nx[k] - oxr[k];
            }
            {
                float ny[12], oyr[12];
                load12(yb + (size_t)(i + 9) * W, ny);
                load12(yb + (size_t)(i + 4) * W, oyr);
                #pragma unroll
                for (int k = 0; k < 12; ++k) cs_y[k] += ny[k] - oyr[k];
            }
        }
    }
}

extern "C" void kernel_launch(void* const* d_in, const int* in_sizes, int n_in,
                              void* d_out, int out_size, void* d_ws, size_t ws_size,
                              hipStream_t stream) {
    const float* x = (const float*)d_in[0];
    const float* y = (const float*)d_in[1];
    // mask (d_in[2]) unused by the reference's channels==1 path
    float* out = (float*)d_out;
    const long long Nper = (long long)out_size / 3;   // elements per output array
    yiq_gngc_w2<<<dim3(NWG), dim3(128), 0, stream>>>(x, y, out, Nper);
}

// Round 14
// 53.640 us; speedup vs baseline: 2.5864x; 1.1133x over previous
//
#include <hip/hip_runtime.h>
#include <math.h>

#define H 1024
#define W 1024
#define OH 1016
#define OW 1016
#define BH 16          // output rows per band; 64 bands (last has 8 valid rows)
#define NBANDS 64
#define NCHUNK 4       // 4 column chunks of 256 output cols
#define NIMG 8
#define NWG (NBANDS*NCHUNK*NIMG)   // 2048, divisible by 8 (bijective XCD swizzle)
#define EPS 1e-6f
#define EPS2 1e-12f    // EPS^2: (vv<EPS) <=> (vx*vy<EPS2)
#define INV25 (1.0f/25.0f)

// R14 = R8 structure (best, 58.9us) with per-wave work reduced:
//  (1) BH 8->16: prologue (34 load12) amortized over 2x rows; 9.75 -> 7.9
//      load12/row (-19% loads). Vertical halo 2.125x -> 1.56x. Tail band
//      handled by block-uniform break + slide guard (i+1<OH).
//  (2) fast finalize: v_rsq_f32 (rsq) replaces precise sqrt+div (~20 VALU ->
//      ~7 per output). Threshold 4.4e-2 >> rsq error. lo-test s<EPS^2 also
//      robustly handles sliding-cancellation s<0.
// Rationale: R6/R7/R8/R13 all ~59-63us while fences/conflicts/FETCH/LDS
// varied -> time tracks per-wave instruction+latency work; wave count is
// pinned (~6/CU) and VALUBusy is residency-invariant (Little's law).
// R5/R9/R12: >~128 live VGPR spills (WRITE sentinel). R6: no sched fences.
// R8: keep XCD swizzle. R11: no raw-row LDS ring.

__device__ __forceinline__ float4 ld4(const float* p){ return *reinterpret_cast<const float4*>(p); }
__device__ __forceinline__ void st4(float* p, float4 v){ *reinterpret_cast<float4*>(p) = v; }

__device__ __forceinline__ void load12(const float* p, float v[12]) {
    float4 a = ld4(p), b = ld4(p + 4), c = ld4(p + 8);
    v[0]=a.x; v[1]=a.y; v[2]=a.z;  v[3]=a.w;
    v[4]=b.x; v[5]=b.y; v[6]=b.z;  v[7]=b.w;
    v[8]=c.x; v[9]=c.y; v[10]=c.z; v[11]=c.w;
}

__global__ __launch_bounds__(64, 2)
void yiq_gngc_b16(const float* __restrict__ x, const float* __restrict__ y,
                  float* __restrict__ out, long long Nper)
{
    __shared__ __align__(16) float ring[5][2][264];   // 10560 B
    const int t = (int)threadIdx.x;

    // ---- XCD-aware bijective swizzle (NWG % 8 == 0) ----
    const int wg  = (int)blockIdx.x;
    const int nid = (wg & 7) * (NWG / 8) + (wg >> 3);
    const int band  = nid % NBANDS;
    const int rest  = nid / NBANDS;        // 0..31
    const int chunk = rest & 3;
    const int b     = rest >> 2;           // image 0..7

    const int jc = chunk * 256;
    const int maxj = (jc + 252 < OW - 4) ? (jc + 252) : (OW - 4);  // 1012 on last chunk
    int j0 = jc + 4 * t; if (j0 > maxj) j0 = maxj;    // clamped lanes duplicate (benign)
    const bool lastlane = (j0 == maxj);               // owns the 4-col ring seam
    const int rel = j0 - jc;                          // 0..252
    const int i0 = band * BH;                         // 0..1008
    const float* xb = x + (size_t)b * (H * W) + j0;
    const float* yb = y + (size_t)b * (H * W) + j0;

    float cs_x[12], cs_y[12];
    float cp1[8], cp2[8], cp3[8];
    #pragma unroll
    for (int k = 0; k < 12; ++k) { cs_x[k] = 0.f; cs_y[k] = 0.f; }
    #pragma unroll
    for (int k = 0; k < 8; ++k) { cp1[k] = 0.f; cp2[k] = 0.f; cp3[k] = 0.f; }

    // ---- zero ring slot 4 (the "row -1" subtracted at it=0) ----
    {
        float4 z = make_float4(0.f, 0.f, 0.f, 0.f);
        st4(&ring[4][0][rel], z); st4(&ring[4][1][rel], z);
        if (lastlane) { st4(&ring[4][0][rel + 4], z); st4(&ring[4][1][rel + 4], z); }
    }

    // ---- initial input column sums over rows i0..i0+4 (x then y) ----
    #pragma unroll
    for (int r = 0; r < 5; ++r) {
        float vx[12];
        load12(xb + (size_t)(i0 + r) * W, vx);
        #pragma unroll
        for (int k = 0; k < 12; ++k) cs_x[k] += vx[k];
    }
    #pragma unroll
    for (int r = 0; r < 5; ++r) {
        float vy[12];
        load12(yb + (size_t)(i0 + r) * W, vy);
        #pragma unroll
        for (int k = 0; k < 12; ++k) cs_y[k] += vy[k];
    }

    // ---- prime dx/dy rows i0..i0+3 into ring slots 0..3; accumulate cp ----
    // (max row touched: i0+8 = 1016 <= 1023)
    #pragma unroll
    for (int pr = 0; pr < 4; ++pr) {
        float xc[12], yc[12];
        load12(xb + (size_t)(i0 + pr + 2) * W, xc);   // center row
        load12(yb + (size_t)(i0 + pr + 2) * W, yc);
        float dxn[8], dyn[8];
        #pragma unroll
        for (int k = 0; k < 8; ++k) {
            float sx = cs_x[k] + cs_x[k+1] + cs_x[k+2] + cs_x[k+3] + cs_x[k+4];
            float sy = cs_y[k] + cs_y[k+1] + cs_y[k+2] + cs_y[k+3] + cs_y[k+4];
            dxn[k] = xc[k + 2] - sx * INV25;
            dyn[k] = yc[k + 2] - sy * INV25;
            cp1[k] += dxn[k] * dyn[k];
            cp2[k] += dxn[k] * dxn[k];
            cp3[k] += dyn[k] * dyn[k];
        }
        st4(&ring[pr][0][rel], make_float4(dxn[0], dxn[1], dxn[2], dxn[3]));
        st4(&ring[pr][1][rel], make_float4(dyn[0], dyn[1], dyn[2], dyn[3]));
        if (lastlane) {
            st4(&ring[pr][0][rel + 4], make_float4(dxn[4], dxn[5], dxn[6], dxn[7]));
            st4(&ring[pr][1][rel + 4], make_float4(dyn[4], dyn[5], dyn[6], dyn[7]));
        }
        // slide cs: add row i0+pr+5, drop row i0+pr (x-pair then y-pair)
        {
            float nx[12], ox[12];
            load12(xb + (size_t)(i0 + pr + 5) * W, nx);
            load12(xb + (size_t)(i0 + pr) * W, ox);
            #pragma unroll
            for (int k = 0; k < 12; ++k) cs_x[k] += nx[k] - ox[k];
        }
        {
            float ny[12], oy[12];
            load12(yb + (size_t)(i0 + pr + 5) * W, ny);
            load12(yb + (size_t)(i0 + pr) * W, oy);
            #pragma unroll
            for (int k = 0; k < 12; ++k) cs_y[k] += ny[k] - oy[k];
        }
    }

    float* ob = out + (size_t)b * ((size_t)OH * OW) + j0;
    int s = 4;   // rotating ring slot (row leaving the window == new row's slot)

    // ---- main loop: output rows i0..i0+BH-1 (tail band breaks at OH) ----
    #pragma unroll 4
    for (int it = 0; it < BH; ++it) {
        const int i = i0 + it;
        if (i >= OH) break;                           // block-uniform (tail band)
        const bool slide = (it < BH - 1) && (i + 1 < OH);  // next iter exists

        // center row for new dx/dy row i+4  (max row 1021)
        float xc[12], yc[12];
        load12(xb + (size_t)(i + 6) * W, xc);
        load12(yb + (size_t)(i + 6) * W, yc);

        // --- old dx/dy (row i-1): own 4 from LDS (same-address as the write
        //     below -> compiler-ordered), halo 4 via shfl from lane t+1 ---
        float4 oox = ld4(&ring[s][0][rel]);
        float4 ooy = ld4(&ring[s][1][rel]);
        float hx0 = __shfl_down(oox.x, 1), hx1 = __shfl_down(oox.y, 1);
        float hx2 = __shfl_down(oox.z, 1), hx3 = __shfl_down(oox.w, 1);
        float hy0 = __shfl_down(ooy.x, 1), hy1 = __shfl_down(ooy.y, 1);
        float hy2 = __shfl_down(ooy.z, 1), hy3 = __shfl_down(ooy.w, 1);
        if (lastlane) {   // seam lane: halo from its own rel+4 slot (same-address ordered)
            float4 dhx = ld4(&ring[s][0][rel + 4]);
            float4 dhy = ld4(&ring[s][1][rel + 4]);
            hx0 = dhx.x; hx1 = dhx.y; hx2 = dhx.z; hx3 = dhx.w;
            hy0 = dhy.x; hy1 = dhy.y; hy2 = dhy.z; hy3 = dhy.w;
        }

        // new dx/dy row i+4 (8 halo cols, in registers)
        float dxn[8], dyn[8];
        #pragma unroll
        for (int k = 0; k < 8; ++k) {
            float sx = cs_x[k] + cs_x[k+1] + cs_x[k+2] + cs_x[k+3] + cs_x[k+4];
            float sy = cs_y[k] + cs_y[k+1] + cs_y[k+2] + cs_y[k+3] + cs_y[k+4];
            dxn[k] = xc[k + 2] - sx * INV25;
            dyn[k] = yc[k + 2] - sy * INV25;
        }
        st4(&ring[s][0][rel], make_float4(dxn[0], dxn[1], dxn[2], dxn[3]));
        st4(&ring[s][1][rel], make_float4(dyn[0], dyn[1], dyn[2], dyn[3]));
        if (lastlane) {
            st4(&ring[s][0][rel + 4], make_float4(dxn[4], dxn[5], dxn[6], dxn[7]));
            st4(&ring[s][1][rel + 4], make_float4(dyn[4], dyn[5], dyn[6], dyn[7]));
        }

        // slide product column sums: + new row, - old row
        float odx[8] = {oox.x, oox.y, oox.z, oox.w, hx0, hx1, hx2, hx3};
        float ody[8] = {ooy.x, ooy.y, ooy.z, ooy.w, hy0, hy1, hy2, hy3};
        #pragma unroll
        for (int k = 0; k < 8; ++k) {
            cp1[k] += dxn[k] * dyn[k] - odx[k] * ody[k];
            cp2[k] += dxn[k] * dxn[k] - odx[k] * odx[k];
            cp3[k] += dyn[k] * dyn[k] - ody[k] * ody[k];
        }

        // finalize output row i, cols j0..j0+3 (fast rsq path)
        float co[4], vv[4], cc[4];
        #pragma unroll
        for (int q = 0; q < 4; ++q) {
            float c_ = (cp1[q] + cp1[q+1] + cp1[q+2] + cp1[q+3] + cp1[q+4]) * INV25;
            float vx = (cp2[q] + cp2[q+1] + cp2[q+2] + cp2[q+3] + cp2[q+4]) * INV25;
            float vy = (cp3[q] + cp3[q+1] + cp3[q+2] + cp3[q+3] + cp3[q+4]) * INV25;
            float sp = vx * vy;
            bool lo  = sp < EPS2;                 // == (sqrt(sp) < EPS); catches sp<0 too
            float r  = __builtin_amdgcn_rsqf(sp); // v_rsq_f32
            float cr = c_ * r;
            cr = cr < 0.f ? 0.f : (cr > 1.f ? 1.f : cr);
            co[q] = lo ? 0.f  : cr;
            vv[q] = lo ? EPS  : sp * r;           // sqrt(sp)
            cc[q] = lo ? 0.f  : c_;
        }
        float* o = ob + (size_t)i * OW;
        st4(o,            make_float4(co[0], co[1], co[2], co[3]));
        st4(o + Nper,     make_float4(vv[0], vv[1], vv[2], vv[3]));
        st4(o + 2 * Nper, make_float4(cc[0], cc[1], cc[2], cc[3]));

        // slide input column sums: add row i+9, drop row i+4 (guarded: i+9<=1023)
        if (slide) {
            {
                float nx[12], oxr[12];
                load12(xb + (size_t)(i + 9) * W, nx);
                load12(xb + (size_t)(i + 4) * W, oxr);
                #pragma unroll
                for (int k = 0; k < 12; ++k) cs_x[k] += nx[k] - oxr[k];
            }
            {
                float ny[12], oyr[12];
                load12(yb + (size_t)(i + 9) * W, ny);
                load12(yb + (size_t)(i + 4) * W, oyr);
                #pragma unroll
                for (int k = 0; k < 12; ++k) cs_y[k] += ny[k] - oyr[k];
            }
        }
        s = (s == 4) ? 0 : s + 1;
    }
}

extern "C" void kernel_launch(void* const* d_in, const int* in_sizes, int n_in,
                              void* d_out, int out_size, void* d_ws, size_t ws_size,
                              hipStream_t stream) {
    const float* x = (const float*)d_in[0];
    const float* y = (const float*)d_in[1];
    // mask (d_in[2]) unused by the reference's channels==1 path
    float* out = (float*)d_out;
    const long long Nper = (long long)out_size / 3;   // elements per output array
    yiq_gngc_b16<<<dim3(NWG), dim3(64), 0, stream>>>(x, y, out, Nper);
}